// Round 11
// baseline (239.245 us; speedup 1.0000x reference)
//
#include <hip/hip_runtime.h>

typedef unsigned int u32;
typedef unsigned short u16;

#define TPB 640
#define TPBC 1024

namespace {
// packed ws layout (f32 offsets). blob = u16[12][307200] = 1,843,200 f32 slots.
// per depth (u32 view, stride 153600): W1g [1280][80 pairs] | W2 [80][640 pairs]
constexpr size_t F_BLOB = 0;
constexpr size_t F_S1   = 1843200;    // f32 [12][160]
constexpr size_t F_T1   = 1845120;    // f32 [12][160]
constexpr size_t F_XI   = 1847040;    // f32 [12][36][768]
constexpr size_t F_XT   = 2178816;    // f32 [12][36][512]
constexpr size_t F_CI   = 2400000;    // f32 [36][768]
constexpr size_t F_CT   = 2427648;    // f32 [36][512]
constexpr size_t F_END  = 2446080;    // 9,784,320 B (proven footprint)
// fallback layout (f32 weights read in place)
constexpr size_t F_XI_U = 0, F_XT_U = 331776, F_CI_U = 552960, F_CT_U = 580608;
}

__device__ __forceinline__ float bflo(u32 u) { return __uint_as_float(u << 16); }
__device__ __forceinline__ float bfhi(u32 u) { return __uint_as_float(u & 0xffff0000u); }
__device__ __forceinline__ float gelu_f(float x) { return 0.5f * x * (1.0f + erff(x * 0.70710678118654752f)); }
__device__ __forceinline__ u16 f2bf(float f) {
    u32 u = __float_as_uint(f);
    u += 0x7fffu + ((u >> 16) & 1u);
    return (u16)(u >> 16);
}

struct P {
    const float *vpc, *vpm, *tpc, *tpm, *cpc, *cpi, *cpt;
    const float *lig, *lib, *ltg, *ltb;
    const float *iw1, *ib1, *iw2, *ib2;
    const float *tw1, *tb1, *tw2, *tb2;
    const float *ciw1, *cib1, *ciw2, *cib2;
    const float *ctw1, *ctb1, *ctw2, *ctb2;
    const u16 *blob;
    const float *s1, *t1;
    float *xi, *xt, *cimg, *ctxt;
};

// ---------------- prep 1: fully-parallel pack (fold LN gamma into W1) ----------------
__global__ __launch_bounds__(256) void prep_pack_kernel(P p, u32* blob32) {
    constexpr u32 N1 = 12u * 1280 * 80;   // W1 u32 pairs
    constexpr u32 N2 = 12u * 80 * 640;    // W2 u32 pairs
    u32 i = blockIdx.x * 256 + threadIdx.x;
    if (i < N1) {
        u32 j2 = i % 80, rem = i / 80;
        u32 k = rem % 1280, d = rem / 1280;
        u32 j0 = 2 * j2;
        const int path = (j0 >= 80);
        const float* W = (path ? p.tw1 : p.iw1) + ((size_t)(d * 1280) + k) * 80 + (j0 - 80 * path);
        float g = (path ? p.ltg : p.lig)[d * 1280 + k];
        float2 v = *reinterpret_cast<const float2*>(W);
        blob32[(size_t)d * 153600 + (size_t)k * 80 + j2] =
            (u32)f2bf(g * v.x) | ((u32)f2bf(g * v.y) << 16);
    } else {
        u32 ii = i - N1;
        if (ii >= N2) return;
        u32 c2 = ii % 640, rem = ii / 640;
        u32 k = rem % 80, d = rem / 80;
        u32 c0 = 2 * c2;
        const float* s = (c0 < 768) ? (p.iw2 + ((size_t)(d * 80) + k) * 768 + c0)
                                    : (p.tw2 + ((size_t)(d * 80) + k) * 512 + (c0 - 768));
        float2 v = *reinterpret_cast<const float2*>(s);
        blob32[(size_t)d * 153600 + 102400 + (size_t)k * 640 + c2] =
            (u32)f2bf(v.x) | ((u32)f2bf(v.y) << 16);
    }
}

// ---------------- prep 2: S1/T1 colsums ----------------
__global__ __launch_bounds__(TPB) void prep_fold_kernel(P p, float* s1o, float* t1o) {
    __shared__ float sA[8][80], sB[8][80];
    const int tid = threadIdx.x;
    const int d = blockIdx.x >> 1, path = blockIdx.x & 1;
    const float* W1 = (path ? p.tw1 : p.iw1) + (size_t)d * 1280 * 80;
    const float* G  = (path ? p.ltg : p.lig) + d * 1280;
    const float* Bb = (path ? p.ltb : p.lib) + d * 1280;
    const int j = tid % 80, kc = tid / 80;    // 8 chunks of 160
    float S = 0.f, T = 0.f;
    for (int k = kc * 160; k < kc * 160 + 160; ++k) {
        float w = W1[(size_t)k * 80 + j];
        S += G[k] * w; T += Bb[k] * w;
    }
    sA[kc][j] = S; sB[kc][j] = T;
    __syncthreads();
    if (tid < 80) {
        float Ss = 0.f, Ts = 0.f;
        #pragma unroll
        for (int q = 0; q < 8; ++q) { Ss += sA[q][tid]; Ts += sB[q][tid]; }
        s1o[d * 160 + path * 80 + tid] = Ss;
        t1o[d * 160 + path * 80 + tid] = Ts + (path ? p.tb1 : p.ib1)[d * 80 + tid];
    }
}

// ---------------- chain: 1024-thread (16-wave) latency-hiding version ----------------
__global__ __launch_bounds__(TPBC, 1) void chain7_kernel(P p) {
    __shared__ float smem[12360];
    float* sx   = smem;            // [1280]
    float* part = smem + 1280;     // [64][160]
    float* red2 = smem + 11520;    // [4][160]
    float* hh   = smem + 12160;    // [160]
    float* redA = smem + 12320;    // [16]
    float* redB = smem + 12336;    // [16]
    float* st   = smem + 12352;    // [2]

    const int tid = threadIdx.x, blk = blockIdx.x;

    if (blk < 36) {
        const int v = blk / 12, t = blk % 12;
        const float* is = (v == 2) ? p.vpm : p.vpc;
        const float* ts = (v == 1) ? p.tpm : p.tpc;
        if (tid < 768) sx[tid] = is[t * 768 + tid];
        if (tid < 512) sx[768 + tid] = ts[t * 512 + tid];
        __syncthreads();

        const u32* blob32 = (const u32*)p.blob;
        const int gi = tid & 15, kc = tid >> 4;   // 16 col-groups x 64 K-chunks
        const int j0 = 10 * gi, k0 = 20 * kc;

        for (int d = 0; d < 12; ++d) {
            // ---- LN stats over raw sx (tid0 computes st; no barrier needed before GEMV1) ----
            {
                float x0 = sx[tid];
                float s = x0, s2 = x0 * x0;
                if (tid < 256) { float x1 = sx[1024 + tid]; s += x1; s2 += x1 * x1; }
                #pragma unroll
                for (int off = 32; off > 0; off >>= 1) { s += __shfl_down(s, off); s2 += __shfl_down(s2, off); }
                if ((tid & 63) == 0) { redA[tid >> 6] = s; redB[tid >> 6] = s2; }
            }
            __syncthreads();
            if (tid == 0) {
                float S = 0.f, S2 = 0.f;
                #pragma unroll
                for (int w = 0; w < 16; ++w) { S += redA[w]; S2 += redB[w]; }
                float m = S * (1.0f / 1280.0f);
                float var = S2 * (1.0f / 1280.0f) - m * m;
                st[0] = m; st[1] = rsqrtf(var + 1e-5f);
            }
            // ---- GEMV1 on raw x (folded weights): 10 cols x 20 K-rows per thread ----
            {
                const u32* wp = blob32 + (size_t)d * 153600 + (size_t)k0 * 80 + 5 * gi;
                float a0 = 0.f, a1 = 0.f, a2 = 0.f, a3 = 0.f, a4 = 0.f;
                float a5 = 0.f, a6 = 0.f, a7 = 0.f, a8 = 0.f, a9 = 0.f;
                #pragma unroll 10
                for (int i = 0; i < 20; ++i) {
                    u32 wA = wp[0], wB = wp[1], wC = wp[2], wD = wp[3], wE = wp[4];
                    float xv = sx[k0 + i];
                    a0 += xv * bflo(wA); a1 += xv * bfhi(wA);
                    a2 += xv * bflo(wB); a3 += xv * bfhi(wB);
                    a4 += xv * bflo(wC); a5 += xv * bfhi(wC);
                    a6 += xv * bflo(wD); a7 += xv * bfhi(wD);
                    a8 += xv * bflo(wE); a9 += xv * bfhi(wE);
                    wp += 80;
                }
                float* pb = part + kc * 160 + j0;
                pb[0] = a0; pb[1] = a1; pb[2] = a2; pb[3] = a3; pb[4] = a4;
                pb[5] = a5; pb[6] = a6; pb[7] = a7; pb[8] = a8; pb[9] = a9;
            }
            __syncthreads();
            // ---- two-stage reduction 64 -> 4 -> 1, then hh ----
            if (tid < 640) {
                const int col = tid % 160, q = tid / 160;
                float y = 0.f;
                #pragma unroll
                for (int j = 0; j < 16; ++j) y += part[(q * 16 + j) * 160 + col];
                red2[q * 160 + col] = y;
            }
            __syncthreads();
            if (tid < 160) {
                float y = red2[tid] + red2[160 + tid] + red2[320 + tid] + red2[480 + tid];
                const float m = st[0], rs = st[1];
                hh[tid] = gelu_f(rs * y - m * rs * p.s1[d * 160 + tid] + p.t1[d * 160 + tid]);
            }
            __syncthreads();
            // ---- GEMV2: 2 cols full-K per thread (u32 loads), 640 active ----
            if (tid < 640) {
                const int c = tid;
                const int pth = (c >= 384);
                const int cc = 2 * c - 768 * pth;
                const float* hb = hh + 80 * pth;
                const u32* wq = blob32 + (size_t)d * 153600 + 102400 + c;
                const float* bb = (pth ? p.tb2 : p.ib2) + d * (pth ? 512 : 768) + cc;
                float a0 = bb[0], a1 = bb[1];
                #pragma unroll 16
                for (int k = 0; k < 80; ++k) {
                    u32 w = *wq;
                    float hv = hb[k];
                    a0 += hv * bflo(w); a1 += hv * bfhi(w);
                    wq += 640;
                }
                sx[2 * c] = a0; sx[2 * c + 1] = a1;
                float* xo = pth ? (p.xt + ((size_t)(d * 36) + blk) * 512 + cc)
                                : (p.xi + ((size_t)(d * 36) + blk) * 768 + cc);
                *reinterpret_cast<float2*>(xo) = make_float2(a0, a1);
            }
            __syncthreads();
        }
    } else {
        // ---- common-prompt MLPs ----
        float* cx  = smem;         // [512]
        float* ph  = smem + 512;   // [4][64]
        float* hhl = smem + 768;   // [64]
        const int rr = blk - 36, v = rr / 12, t = rr % 12;
        const float* cs = (v == 0) ? p.cpc : (v == 1) ? p.cpi : p.cpt;
        if (tid < 512) cx[tid] = cs[t * 512 + tid];
        __syncthreads();
        if (tid < 256) {
            const int o = tid & 63, kcq = tid >> 6;
            const int path = o >> 5, j = o & 31;
            const float* w = (path ? p.ctw1 : p.ciw1) + (size_t)(kcq * 128) * 32 + j;
            float a = 0.f;
            #pragma unroll 8
            for (int i = 0; i < 128; ++i) { a += cx[kcq * 128 + i] * (*w); w += 32; }
            ph[kcq * 64 + o] = a;
        }
        __syncthreads();
        if (tid < 64) {
            const int path = tid >> 5, j = tid & 31;
            float a = (path ? p.ctb1 : p.cib1)[j];
            #pragma unroll
            for (int q = 0; q < 4; ++q) a += ph[q * 64 + tid];
            hhl[tid] = gelu_f(a);
        }
        __syncthreads();
        for (int o = tid; o < 1280; o += TPBC) {
            if (o < 768) {
                float a = p.cib2[o];
                #pragma unroll
                for (int k = 0; k < 32; ++k) a += hhl[k] * p.ciw2[k * 768 + o];
                p.cimg[rr * 768 + o] = a;
            } else {
                const int oo = o - 768;
                float a = p.ctb2[oo];
                #pragma unroll
                for (int k = 0; k < 32; ++k) a += hhl[32 + k] * p.ctw2[k * 512 + oo];
                p.ctxt[rr * 512 + oo] = a;
            }
        }
    }
}

// ---------------- fallback chain (f32 weights in place; r4-proven) ----------------
__global__ __launch_bounds__(TPB) void chain_fb_kernel(P p) {
    __shared__ float smem[6592];
    float* sx   = smem;
    float* xln0 = smem + 1280;
    float* xln1 = smem + 2560;
    float* part = smem + 3840;
    float* hh   = smem + 6400;
    float* redA = smem + 6560;
    float* redB = smem + 6570;
    float* st   = smem + 6580;
    const int tid = threadIdx.x, blk = blockIdx.x;
    if (blk < 36) {
        const int v = blk / 12, t = blk % 12;
        const float* is = (v == 2) ? p.vpm : p.vpc;
        const float* ts = (v == 1) ? p.tpm : p.tpc;
        if (tid < 512) sx[768 + tid] = ts[t * 512 + tid];
        for (int k = tid; k < 768; k += TPB) sx[k] = is[t * 768 + k];
        __syncthreads();
        for (int d = 0; d < 12; ++d) {
            {
                float x0 = sx[tid], x1 = sx[tid + 640];
                float s = x0 + x1, s2 = x0 * x0 + x1 * x1;
                #pragma unroll
                for (int off = 32; off > 0; off >>= 1) { s += __shfl_down(s, off); s2 += __shfl_down(s2, off); }
                if ((tid & 63) == 0) { redA[tid >> 6] = s; redB[tid >> 6] = s2; }
            }
            __syncthreads();
            if (tid == 0) {
                float S = 0.f, S2 = 0.f;
                #pragma unroll
                for (int w = 0; w < 10; ++w) { S += redA[w]; S2 += redB[w]; }
                float m = S * (1.0f / 1280.0f);
                float var = S2 * (1.0f / 1280.0f) - m * m;
                st[0] = m; st[1] = rsqrtf(var + 1e-5f);
            }
            __syncthreads();
            const float m = st[0], rs = st[1];
            #pragma unroll
            for (int q = 0; q < 2; ++q) {
                const int k = tid + 640 * q;
                float xc = (sx[k] - m) * rs;
                xln0[k] = xc * p.lig[d * 1280 + k] + p.lib[d * 1280 + k];
                xln1[k] = xc * p.ltg[d * 1280 + k] + p.ltb[d * 1280 + k];
            }
            __syncthreads();
            {
                const int g = tid % 40, kcq = tid / 40;
                const int j0 = 4 * g;
                const float* xl = (j0 >= 80) ? xln1 : xln0;
                const int k0 = kcq * 80;
                float a0 = 0.f, a1 = 0.f, a2 = 0.f, a3 = 0.f;
                const float* wp = (j0 < 80) ? (p.iw1 + ((size_t)(d * 1280) + k0) * 80 + j0)
                                            : (p.tw1 + ((size_t)(d * 1280) + k0) * 80 + (j0 - 80));
                #pragma unroll 8
                for (int i = 0; i < 80; ++i) {
                    float4 w = *reinterpret_cast<const float4*>(wp);
                    float xv = xl[k0 + i];
                    a0 += xv * w.x; a1 += xv * w.y; a2 += xv * w.z; a3 += xv * w.w;
                    wp += 80;
                }
                *reinterpret_cast<float4*>(part + kcq * 160 + j0) = make_float4(a0, a1, a2, a3);
            }
            __syncthreads();
            if (tid < 160) {
                const int path = tid >= 80, j = tid - 80 * path;
                float a = (path ? p.tb1 : p.ib1)[d * 80 + j];
                #pragma unroll
                for (int q = 0; q < 16; ++q) a += part[q * 160 + tid];
                hh[tid] = gelu_f(a);
            }
            __syncthreads();
            {
                const int c = tid;
                const int pth = (c >= 384);
                const int cc = 2 * c - 768 * pth;
                const float* hb = hh + 80 * pth;
                const int Np = pth ? 512 : 768;
                const float* b2 = (pth ? p.tb2 : p.ib2) + d * Np + cc;
                float a0 = b2[0], a1 = b2[1];
                const float* wp = (pth ? p.tw2 + (size_t)(d * 80) * 512 : p.iw2 + (size_t)(d * 80) * 768) + cc;
                #pragma unroll 16
                for (int k = 0; k < 80; ++k) {
                    float2 w = *reinterpret_cast<const float2*>(wp);
                    float hv = hb[k];
                    a0 += hv * w.x; a1 += hv * w.y;
                    wp += Np;
                }
                sx[2 * c] = a0; sx[2 * c + 1] = a1;
                float* xo = pth ? (p.xt + ((size_t)(d * 36) + blk) * 512 + cc)
                                : (p.xi + ((size_t)(d * 36) + blk) * 768 + cc);
                *reinterpret_cast<float2*>(xo) = make_float2(a0, a1);
            }
            __syncthreads();
        }
    } else {
        float* cx  = smem;
        float* ph  = smem + 512;
        float* hhl = smem + 768;
        const int rr = blk - 36, v = rr / 12, t = rr % 12;
        const float* cs = (v == 0) ? p.cpc : (v == 1) ? p.cpi : p.cpt;
        if (tid < 512) cx[tid] = cs[t * 512 + tid];
        __syncthreads();
        if (tid < 256) {
            const int o = tid & 63, kcq = tid >> 6;
            const int path = o >> 5, j = o & 31;
            const float* w = (path ? p.ctw1 : p.ciw1) + (size_t)(kcq * 128) * 32 + j;
            float a = 0.f;
            #pragma unroll 8
            for (int i = 0; i < 128; ++i) { a += cx[kcq * 128 + i] * (*w); w += 32; }
            ph[kcq * 64 + o] = a;
        }
        __syncthreads();
        if (tid < 64) {
            const int path = tid >> 5, j = tid & 31;
            float a = (path ? p.ctb1 : p.cib1)[j];
            #pragma unroll
            for (int q = 0; q < 4; ++q) a += ph[q * 64 + tid];
            hhl[tid] = gelu_f(a);
        }
        __syncthreads();
        for (int o = tid; o < 1280; o += TPB) {
            if (o < 768) {
                float a = p.cib2[o];
                #pragma unroll
                for (int k = 0; k < 32; ++k) a += hhl[k] * p.ciw2[k * 768 + o];
                p.cimg[rr * 768 + o] = a;
            } else {
                const int oo = o - 768;
                float a = p.ctb2[oo];
                #pragma unroll
                for (int k = 0; k < 32; ++k) a += hhl[32 + k] * p.ctw2[k * 512 + oo];
                p.ctxt[rr * 512 + oo] = a;
            }
        }
    }
}

// ---------------- emit: 8 f32 (32 B) per thread-iteration ----------------
__global__ __launch_bounds__(256) void emit_kernel(const int* __restrict__ mt,
                                                   const float* __restrict__ xi,
                                                   const float* __restrict__ xt,
                                                   const float* __restrict__ cimg,
                                                   const float* __restrict__ ctxt,
                                                   float* __restrict__ out) {
    constexpr unsigned int C0 = 512u * 24 * 96;        // img0  [512][24][768] /8
    constexpr unsigned int C1 = 512u * 24 * 64;        // txt0  [512][24][512] /8
    constexpr unsigned int C2 = 11u * 512 * 12 * 96;   // imgs  /8
    constexpr unsigned int C3 = 11u * 512 * 12 * 64;   // txts  /8
    constexpr unsigned int TOT = C0 + C1 + C2 + C3;    // 12,779,520
    const unsigned int stride = gridDim.x * blockDim.x;
    for (unsigned int c = blockIdx.x * blockDim.x + threadIdx.x; c < TOT; c += stride) {
        const float* src;
        if (c < C0) {
            unsigned int b = c / 2304u, r = c % 2304u;          // 24*96
            unsigned int tok = r / 96u, col = (r % 96u) * 8u;
            int v = mt[b];
            src = (tok < 12u) ? xi + ((size_t)v * 12 + tok) * 768 + col
                              : cimg + ((size_t)v * 12 + (tok - 12u)) * 768 + col;
        } else if (c < C0 + C1) {
            unsigned int cc = c - C0;
            unsigned int b = cc / 1536u, r = cc % 1536u;        // 24*64
            unsigned int tok = r / 64u, col = (r % 64u) * 8u;
            int v = mt[b];
            src = (tok < 12u) ? xt + ((size_t)v * 12 + tok) * 512 + col
                              : ctxt + ((size_t)v * 12 + (tok - 12u)) * 512 + col;
        } else if (c < C0 + C1 + C2) {
            unsigned int cc = c - C0 - C1;
            unsigned int d = cc / 589824u, r = cc % 589824u;    // 512*12*96
            unsigned int b = r / 1152u, rr = r % 1152u;         // 12*96
            unsigned int tok = rr / 96u, col = (rr % 96u) * 8u;
            int v = mt[b];
            src = xi + ((size_t)(d + 1) * 36 + v * 12 + tok) * 768 + col;
        } else {
            unsigned int cc = c - C0 - C1 - C2;
            unsigned int d = cc / 393216u, r = cc % 393216u;    // 512*12*64
            unsigned int b = r / 768u, rr = r % 768u;           // 12*64
            unsigned int tok = rr / 64u, col = (rr % 64u) * 8u;
            int v = mt[b];
            src = xt + ((size_t)(d + 1) * 36 + v * 12 + tok) * 512 + col;
        }
        float4 f0 = *reinterpret_cast<const float4*>(src);
        float4 f1 = *reinterpret_cast<const float4*>(src + 4);
        float* dst = out + (size_t)c * 8;
        *reinterpret_cast<float4*>(dst)     = f0;
        *reinterpret_cast<float4*>(dst + 4) = f1;
    }
}

extern "C" void kernel_launch(void* const* d_in, const int* in_sizes, int n_in,
                              void* d_out, int out_size, void* d_ws, size_t ws_size,
                              hipStream_t stream) {
    const int* mt = (const int*)d_in[0];
    float* ws = (float*)d_ws;
    P p;
    p.vpc  = (const float*)d_in[1];
    p.vpm  = (const float*)d_in[2];
    p.tpc  = (const float*)d_in[3];
    p.tpm  = (const float*)d_in[4];
    p.cpc  = (const float*)d_in[5];
    p.cpi  = (const float*)d_in[6];
    p.cpt  = (const float*)d_in[7];
    p.lig  = (const float*)d_in[8];
    p.lib  = (const float*)d_in[9];
    p.ltg  = (const float*)d_in[10];
    p.ltb  = (const float*)d_in[11];
    p.iw1  = (const float*)d_in[12];
    p.ib1  = (const float*)d_in[13];
    p.iw2  = (const float*)d_in[14];
    p.ib2  = (const float*)d_in[15];
    p.tw1  = (const float*)d_in[16];
    p.tb1  = (const float*)d_in[17];
    p.tw2  = (const float*)d_in[18];
    p.tb2  = (const float*)d_in[19];
    p.ciw1 = (const float*)d_in[20];
    p.cib1 = (const float*)d_in[21];
    p.ciw2 = (const float*)d_in[22];
    p.cib2 = (const float*)d_in[23];
    p.ctw1 = (const float*)d_in[24];
    p.ctb1 = (const float*)d_in[25];
    p.ctw2 = (const float*)d_in[26];
    p.ctb2 = (const float*)d_in[27];

    const bool packed = (ws_size >= F_END * sizeof(float));
    if (packed) {
        p.blob = (const u16*)(ws + F_BLOB);
        p.s1   = ws + F_S1;
        p.t1   = ws + F_T1;
        p.xi   = ws + F_XI;
        p.xt   = ws + F_XT;
        p.cimg = ws + F_CI;
        p.ctxt = ws + F_CT;
        constexpr u32 NPAIR = 12u * 1280 * 80 + 12u * 80 * 640;
        prep_pack_kernel<<<dim3((NPAIR + 255) / 256), dim3(256), 0, stream>>>(p, (u32*)(ws + F_BLOB));
        prep_fold_kernel<<<dim3(24), dim3(TPB), 0, stream>>>(p, ws + F_S1, ws + F_T1);
        chain7_kernel<<<dim3(72), dim3(TPBC), 0, stream>>>(p);
    } else {
        p.blob = nullptr; p.s1 = nullptr; p.t1 = nullptr;
        p.xi   = ws + F_XI_U;
        p.xt   = ws + F_XT_U;
        p.cimg = ws + F_CI_U;
        p.ctxt = ws + F_CT_U;
        chain_fb_kernel<<<dim3(72), dim3(TPB), 0, stream>>>(p);
    }
    emit_kernel<<<dim3(4096), dim3(256), 0, stream>>>(mt, p.xi, p.xt, p.cimg, p.ctxt, (float*)d_out);
}

// Round 12
// 220.985 us; speedup vs baseline: 1.0826x; 1.0826x over previous
//
#include <hip/hip_runtime.h>

typedef unsigned int u32;
typedef unsigned short u16;

#define TPB 640

namespace {
// packed ws layout (f32 offsets). blob = u16[12][307200] = 1,843,200 f32 slots.
// per depth (u32 view, stride 153600): W1g [1280][80 pairs] | W2 [80][640 pairs]
constexpr size_t F_BLOB = 0;
constexpr size_t F_S1   = 1843200;    // f32 [12][160]
constexpr size_t F_T1   = 1845120;    // f32 [12][160]
constexpr size_t F_XI   = 1847040;    // f32 [12][36][768]
constexpr size_t F_XT   = 2178816;    // f32 [12][36][512]
constexpr size_t F_CI   = 2400000;    // f32 [36][768]
constexpr size_t F_CT   = 2427648;    // f32 [36][512]
constexpr size_t F_END  = 2446080;    // 9,784,320 B (proven footprint)
// fallback layout (f32 weights read in place)
constexpr size_t F_XI_U = 0, F_XT_U = 331776, F_CI_U = 552960, F_CT_U = 580608;
}

__device__ __forceinline__ float bflo(u32 u) { return __uint_as_float(u << 16); }
__device__ __forceinline__ float bfhi(u32 u) { return __uint_as_float(u & 0xffff0000u); }
__device__ __forceinline__ float gelu_f(float x) { return 0.5f * x * (1.0f + erff(x * 0.70710678118654752f)); }
__device__ __forceinline__ u16 f2bf(float f) {
    u32 u = __float_as_uint(f);
    u += 0x7fffu + ((u >> 16) & 1u);
    return (u16)(u >> 16);
}

struct P {
    const float *vpc, *vpm, *tpc, *tpm, *cpc, *cpi, *cpt;
    const float *lig, *lib, *ltg, *ltb;
    const float *iw1, *ib1, *iw2, *ib2;
    const float *tw1, *tb1, *tw2, *tb2;
    const float *ciw1, *cib1, *ciw2, *cib2;
    const float *ctw1, *ctb1, *ctw2, *ctb2;
    const u16 *blob;
    const float *s1, *t1;
    float *xi, *xt, *cimg, *ctxt;
};

// ---------------- prep 1: fully-parallel pack (fold LN gamma into W1) ----------------
__global__ __launch_bounds__(256) void prep_pack_kernel(P p, u32* blob32) {
    constexpr u32 N1 = 12u * 1280 * 80;   // W1 u32 pairs
    constexpr u32 N2 = 12u * 80 * 640;    // W2 u32 pairs
    u32 i = blockIdx.x * 256 + threadIdx.x;
    if (i < N1) {
        u32 j2 = i % 80, rem = i / 80;
        u32 k = rem % 1280, d = rem / 1280;
        u32 j0 = 2 * j2;
        const int path = (j0 >= 80);
        const float* W = (path ? p.tw1 : p.iw1) + ((size_t)(d * 1280) + k) * 80 + (j0 - 80 * path);
        float g = (path ? p.ltg : p.lig)[d * 1280 + k];
        float2 v = *reinterpret_cast<const float2*>(W);
        blob32[(size_t)d * 153600 + (size_t)k * 80 + j2] =
            (u32)f2bf(g * v.x) | ((u32)f2bf(g * v.y) << 16);
    } else {
        u32 ii = i - N1;
        if (ii >= N2) return;
        u32 c2 = ii % 640, rem = ii / 640;
        u32 k = rem % 80, d = rem / 80;
        u32 c0 = 2 * c2;
        const float* s = (c0 < 768) ? (p.iw2 + ((size_t)(d * 80) + k) * 768 + c0)
                                    : (p.tw2 + ((size_t)(d * 80) + k) * 512 + (c0 - 768));
        float2 v = *reinterpret_cast<const float2*>(s);
        blob32[(size_t)d * 153600 + 102400 + (size_t)k * 640 + c2] =
            (u32)f2bf(v.x) | ((u32)f2bf(v.y) << 16);
    }
}

// ---------------- prep 2: S1/T1 colsums ----------------
__global__ __launch_bounds__(TPB) void prep_fold_kernel(P p, float* s1o, float* t1o) {
    __shared__ float sA[8][80], sB[8][80];
    const int tid = threadIdx.x;
    const int d = blockIdx.x >> 1, path = blockIdx.x & 1;
    const float* W1 = (path ? p.tw1 : p.iw1) + (size_t)d * 1280 * 80;
    const float* G  = (path ? p.ltg : p.lig) + d * 1280;
    const float* Bb = (path ? p.ltb : p.lib) + d * 1280;
    const int j = tid % 80, kc = tid / 80;    // 8 chunks of 160
    float S = 0.f, T = 0.f;
    for (int k = kc * 160; k < kc * 160 + 160; ++k) {
        float w = W1[(size_t)k * 80 + j];
        S += G[k] * w; T += Bb[k] * w;
    }
    sA[kc][j] = S; sB[kc][j] = T;
    __syncthreads();
    if (tid < 80) {
        float Ss = 0.f, Ts = 0.f;
        #pragma unroll
        for (int q = 0; q < 8; ++q) { Ss += sA[q][tid]; Ts += sB[q][tid]; }
        s1o[d * 160 + path * 80 + tid] = Ss;
        t1o[d * 160 + path * 80 + tid] = Ts + (path ? p.tb1 : p.ib1)[d * 80 + tid];
    }
}

// ---------------- chain: r10 skeleton + relaxed VGPR cap + deep load batching ----------------
__global__ __launch_bounds__(TPB, 1) void chain8_kernel(P p) {
    __shared__ float smem[4032];
    float* sx   = smem;           // [1280] raw x
    float* part = smem + 1280;    // [16][160]
    float* hh   = smem + 3840;    // [160]
    float* redA = smem + 4000;    // [10]
    float* redB = smem + 4010;    // [10]
    float* st   = smem + 4020;    // [2]

    const int tid = threadIdx.x, blk = blockIdx.x;

    if (blk < 36) {
        const int v = blk / 12, t = blk % 12;
        const float* is = (v == 2) ? p.vpm : p.vpc;
        const float* ts = (v == 1) ? p.tpm : p.tpc;
        for (int k = tid; k < 768; k += TPB) sx[k] = is[t * 768 + k];
        if (tid < 512) sx[768 + tid] = ts[t * 512 + tid];
        __syncthreads();

        const u32* blob32 = (const u32*)p.blob;
        const int g = tid % 40, kc = tid / 40;   // GEMV1: 4 cols x 16 K-chunks of 80
        const int j0 = 4 * g;

        for (int d = 0; d < 12; ++d) {
            // ---- LN stats over raw sx ----
            {
                float x0 = sx[tid], x1 = sx[tid + 640];
                float s = x0 + x1, s2 = x0 * x0 + x1 * x1;
                #pragma unroll
                for (int off = 32; off > 0; off >>= 1) { s += __shfl_down(s, off); s2 += __shfl_down(s2, off); }
                if ((tid & 63) == 0) { redA[tid >> 6] = s; redB[tid >> 6] = s2; }
            }
            __syncthreads();
            if (tid == 0) {
                float S = 0.f, S2 = 0.f;
                #pragma unroll
                for (int w = 0; w < 10; ++w) { S += redA[w]; S2 += redB[w]; }
                float m = S * (1.0f / 1280.0f);
                float var = S2 * (1.0f / 1280.0f) - m * m;
                st[0] = m; st[1] = rsqrtf(var + 1e-5f);
            }
            // ---- GEMV1 on raw x: 4 batches x 20 uint2 loads issued before use ----
            {
                const int k0 = kc * 80;
                const u32* wp = blob32 + (size_t)d * 153600 + (size_t)k0 * 80 + 2 * g;
                float a0 = 0.f, a1 = 0.f, a2 = 0.f, a3 = 0.f;
                #pragma unroll
                for (int ib = 0; ib < 4; ++ib) {
                    uint2 wreg[20];
                    #pragma unroll
                    for (int i = 0; i < 20; ++i)
                        wreg[i] = *reinterpret_cast<const uint2*>(wp + (size_t)(ib * 20 + i) * 80);
                    #pragma unroll
                    for (int i = 0; i < 20; ++i) {
                        float xv = sx[k0 + ib * 20 + i];
                        a0 += xv * bflo(wreg[i].x); a1 += xv * bfhi(wreg[i].x);
                        a2 += xv * bflo(wreg[i].y); a3 += xv * bfhi(wreg[i].y);
                    }
                }
                *reinterpret_cast<float4*>(part + kc * 160 + j0) = make_float4(a0, a1, a2, a3);
            }
            __syncthreads();
            if (tid < 160) {
                float y = 0.f;
                #pragma unroll
                for (int q = 0; q < 16; ++q) y += part[q * 160 + tid];
                const float m = st[0], rs = st[1];
                hh[tid] = gelu_f(rs * y - m * rs * p.s1[d * 160 + tid] + p.t1[d * 160 + tid]);
            }
            __syncthreads();
            // ---- GEMV2: 5 batches x 16 u32 loads issued before use ----
            {
                const int c = tid;
                const int pth = (c >= 384);
                const int cc = 2 * c - 768 * pth;
                const float* hb = hh + 80 * pth;
                const u32* wq = blob32 + (size_t)d * 153600 + 102400 + c;
                const float* bb = (pth ? p.tb2 : p.ib2) + d * (pth ? 512 : 768) + cc;
                float a0 = bb[0], a1 = bb[1];
                #pragma unroll
                for (int ib = 0; ib < 5; ++ib) {
                    u32 wreg[16];
                    #pragma unroll
                    for (int i = 0; i < 16; ++i) wreg[i] = wq[(size_t)(ib * 16 + i) * 640];
                    #pragma unroll
                    for (int i = 0; i < 16; ++i) {
                        float hv = hb[ib * 16 + i];
                        a0 += hv * bflo(wreg[i]); a1 += hv * bfhi(wreg[i]);
                    }
                }
                sx[2 * c] = a0; sx[2 * c + 1] = a1;
                float* xo = pth ? (p.xt + ((size_t)(d * 36) + blk) * 512 + cc)
                                : (p.xi + ((size_t)(d * 36) + blk) * 768 + cc);
                *reinterpret_cast<float2*>(xo) = make_float2(a0, a1);
            }
            __syncthreads();
        }
    } else {
        // ---- common-prompt MLPs ----
        float* cx  = smem;         // [512]
        float* ph  = smem + 512;   // [4][64]
        float* hhl = smem + 768;   // [64]
        const int rr = blk - 36, v = rr / 12, t = rr % 12;
        const float* cs = (v == 0) ? p.cpc : (v == 1) ? p.cpi : p.cpt;
        if (tid < 512) cx[tid] = cs[t * 512 + tid];
        __syncthreads();
        if (tid < 256) {
            const int o = tid & 63, kcq = tid >> 6;
            const int path = o >> 5, j = o & 31;
            const float* w = (path ? p.ctw1 : p.ciw1) + (size_t)(kcq * 128) * 32 + j;
            float a = 0.f;
            #pragma unroll 8
            for (int i = 0; i < 128; ++i) { a += cx[kcq * 128 + i] * (*w); w += 32; }
            ph[kcq * 64 + o] = a;
        }
        __syncthreads();
        if (tid < 64) {
            const int path = tid >> 5, j = tid & 31;
            float a = (path ? p.ctb1 : p.cib1)[j];
            #pragma unroll
            for (int q = 0; q < 4; ++q) a += ph[q * 64 + tid];
            hhl[tid] = gelu_f(a);
        }
        __syncthreads();
        for (int o = tid; o < 1280; o += TPB) {
            if (o < 768) {
                float a = p.cib2[o];
                #pragma unroll
                for (int k = 0; k < 32; ++k) a += hhl[k] * p.ciw2[k * 768 + o];
                p.cimg[rr * 768 + o] = a;
            } else {
                const int oo = o - 768;
                float a = p.ctb2[oo];
                #pragma unroll
                for (int k = 0; k < 32; ++k) a += hhl[32 + k] * p.ctw2[k * 512 + oo];
                p.ctxt[rr * 512 + oo] = a;
            }
        }
    }
}

// ---------------- fallback chain (f32 weights in place; r4-proven) ----------------
__global__ __launch_bounds__(TPB) void chain_fb_kernel(P p) {
    __shared__ float smem[6592];
    float* sx   = smem;
    float* xln0 = smem + 1280;
    float* xln1 = smem + 2560;
    float* part = smem + 3840;
    float* hh   = smem + 6400;
    float* redA = smem + 6560;
    float* redB = smem + 6570;
    float* st   = smem + 6580;
    const int tid = threadIdx.x, blk = blockIdx.x;
    if (blk < 36) {
        const int v = blk / 12, t = blk % 12;
        const float* is = (v == 2) ? p.vpm : p.vpc;
        const float* ts = (v == 1) ? p.tpm : p.tpc;
        if (tid < 512) sx[768 + tid] = ts[t * 512 + tid];
        for (int k = tid; k < 768; k += TPB) sx[k] = is[t * 768 + k];
        __syncthreads();
        for (int d = 0; d < 12; ++d) {
            {
                float x0 = sx[tid], x1 = sx[tid + 640];
                float s = x0 + x1, s2 = x0 * x0 + x1 * x1;
                #pragma unroll
                for (int off = 32; off > 0; off >>= 1) { s += __shfl_down(s, off); s2 += __shfl_down(s2, off); }
                if ((tid & 63) == 0) { redA[tid >> 6] = s; redB[tid >> 6] = s2; }
            }
            __syncthreads();
            if (tid == 0) {
                float S = 0.f, S2 = 0.f;
                #pragma unroll
                for (int w = 0; w < 10; ++w) { S += redA[w]; S2 += redB[w]; }
                float m = S * (1.0f / 1280.0f);
                float var = S2 * (1.0f / 1280.0f) - m * m;
                st[0] = m; st[1] = rsqrtf(var + 1e-5f);
            }
            __syncthreads();
            const float m = st[0], rs = st[1];
            #pragma unroll
            for (int q = 0; q < 2; ++q) {
                const int k = tid + 640 * q;
                float xc = (sx[k] - m) * rs;
                xln0[k] = xc * p.lig[d * 1280 + k] + p.lib[d * 1280 + k];
                xln1[k] = xc * p.ltg[d * 1280 + k] + p.ltb[d * 1280 + k];
            }
            __syncthreads();
            {
                const int g = tid % 40, kcq = tid / 40;
                const int j0 = 4 * g;
                const float* xl = (j0 >= 80) ? xln1 : xln0;
                const int k0 = kcq * 80;
                float a0 = 0.f, a1 = 0.f, a2 = 0.f, a3 = 0.f;
                const float* wp = (j0 < 80) ? (p.iw1 + ((size_t)(d * 1280) + k0) * 80 + j0)
                                            : (p.tw1 + ((size_t)(d * 1280) + k0) * 80 + (j0 - 80));
                #pragma unroll 8
                for (int i = 0; i < 80; ++i) {
                    float4 w = *reinterpret_cast<const float4*>(wp);
                    float xv = xl[k0 + i];
                    a0 += xv * w.x; a1 += xv * w.y; a2 += xv * w.z; a3 += xv * w.w;
                    wp += 80;
                }
                *reinterpret_cast<float4*>(part + kcq * 160 + j0) = make_float4(a0, a1, a2, a3);
            }
            __syncthreads();
            if (tid < 160) {
                const int path = tid >= 80, j = tid - 80 * path;
                float a = (path ? p.tb1 : p.ib1)[d * 80 + j];
                #pragma unroll
                for (int q = 0; q < 16; ++q) a += part[q * 160 + tid];
                hh[tid] = gelu_f(a);
            }
            __syncthreads();
            {
                const int c = tid;
                const int pth = (c >= 384);
                const int cc = 2 * c - 768 * pth;
                const float* hb = hh + 80 * pth;
                const int Np = pth ? 512 : 768;
                const float* b2 = (pth ? p.tb2 : p.ib2) + d * Np + cc;
                float a0 = b2[0], a1 = b2[1];
                const float* wp = (pth ? p.tw2 + (size_t)(d * 80) * 512 : p.iw2 + (size_t)(d * 80) * 768) + cc;
                #pragma unroll 16
                for (int k = 0; k < 80; ++k) {
                    float2 w = *reinterpret_cast<const float2*>(wp);
                    float hv = hb[k];
                    a0 += hv * w.x; a1 += hv * w.y;
                    wp += Np;
                }
                sx[2 * c] = a0; sx[2 * c + 1] = a1;
                float* xo = pth ? (p.xt + ((size_t)(d * 36) + blk) * 512 + cc)
                                : (p.xi + ((size_t)(d * 36) + blk) * 768 + cc);
                *reinterpret_cast<float2*>(xo) = make_float2(a0, a1);
            }
            __syncthreads();
        }
    } else {
        float* cx  = smem;
        float* ph  = smem + 512;
        float* hhl = smem + 768;
        const int rr = blk - 36, v = rr / 12, t = rr % 12;
        const float* cs = (v == 0) ? p.cpc : (v == 1) ? p.cpi : p.cpt;
        if (tid < 512) cx[tid] = cs[t * 512 + tid];
        __syncthreads();
        if (tid < 256) {
            const int o = tid & 63, kcq = tid >> 6;
            const int path = o >> 5, j = o & 31;
            const float* w = (path ? p.ctw1 : p.ciw1) + (size_t)(kcq * 128) * 32 + j;
            float a = 0.f;
            #pragma unroll 8
            for (int i = 0; i < 128; ++i) { a += cx[kcq * 128 + i] * (*w); w += 32; }
            ph[kcq * 64 + o] = a;
        }
        __syncthreads();
        if (tid < 64) {
            const int path = tid >> 5, j = tid & 31;
            float a = (path ? p.ctb1 : p.cib1)[j];
            #pragma unroll
            for (int q = 0; q < 4; ++q) a += ph[q * 64 + tid];
            hhl[tid] = gelu_f(a);
        }
        __syncthreads();
        for (int o = tid; o < 1280; o += TPB) {
            if (o < 768) {
                float a = p.cib2[o];
                #pragma unroll
                for (int k = 0; k < 32; ++k) a += hhl[k] * p.ciw2[k * 768 + o];
                p.cimg[rr * 768 + o] = a;
            } else {
                const int oo = o - 768;
                float a = p.ctb2[oo];
                #pragma unroll
                for (int k = 0; k < 32; ++k) a += hhl[32 + k] * p.ctw2[k * 512 + oo];
                p.ctxt[rr * 512 + oo] = a;
            }
        }
    }
}

// ---------------- emit: 8 f32 (32 B) per thread-iteration ----------------
__global__ __launch_bounds__(256) void emit_kernel(const int* __restrict__ mt,
                                                   const float* __restrict__ xi,
                                                   const float* __restrict__ xt,
                                                   const float* __restrict__ cimg,
                                                   const float* __restrict__ ctxt,
                                                   float* __restrict__ out) {
    constexpr unsigned int C0 = 512u * 24 * 96;        // img0  [512][24][768] /8
    constexpr unsigned int C1 = 512u * 24 * 64;        // txt0  [512][24][512] /8
    constexpr unsigned int C2 = 11u * 512 * 12 * 96;   // imgs  /8
    constexpr unsigned int C3 = 11u * 512 * 12 * 64;   // txts  /8
    constexpr unsigned int TOT = C0 + C1 + C2 + C3;    // 12,779,520
    const unsigned int stride = gridDim.x * blockDim.x;
    for (unsigned int c = blockIdx.x * blockDim.x + threadIdx.x; c < TOT; c += stride) {
        const float* src;
        if (c < C0) {
            unsigned int b = c / 2304u, r = c % 2304u;          // 24*96
            unsigned int tok = r / 96u, col = (r % 96u) * 8u;
            int v = mt[b];
            src = (tok < 12u) ? xi + ((size_t)v * 12 + tok) * 768 + col
                              : cimg + ((size_t)v * 12 + (tok - 12u)) * 768 + col;
        } else if (c < C0 + C1) {
            unsigned int cc = c - C0;
            unsigned int b = cc / 1536u, r = cc % 1536u;        // 24*64
            unsigned int tok = r / 64u, col = (r % 64u) * 8u;
            int v = mt[b];
            src = (tok < 12u) ? xt + ((size_t)v * 12 + tok) * 512 + col
                              : ctxt + ((size_t)v * 12 + (tok - 12u)) * 512 + col;
        } else if (c < C0 + C1 + C2) {
            unsigned int cc = c - C0 - C1;
            unsigned int d = cc / 589824u, r = cc % 589824u;    // 512*12*96
            unsigned int b = r / 1152u, rr = r % 1152u;         // 12*96
            unsigned int tok = rr / 96u, col = (rr % 96u) * 8u;
            int v = mt[b];
            src = xi + ((size_t)(d + 1) * 36 + v * 12 + tok) * 768 + col;
        } else {
            unsigned int cc = c - C0 - C1 - C2;
            unsigned int d = cc / 393216u, r = cc % 393216u;    // 512*12*64
            unsigned int b = r / 768u, rr = r % 768u;           // 12*64
            unsigned int tok = rr / 64u, col = (rr % 64u) * 8u;
            int v = mt[b];
            src = xt + ((size_t)(d + 1) * 36 + v * 12 + tok) * 512 + col;
        }
        float4 f0 = *reinterpret_cast<const float4*>(src);
        float4 f1 = *reinterpret_cast<const float4*>(src + 4);
        float* dst = out + (size_t)c * 8;
        *reinterpret_cast<float4*>(dst)     = f0;
        *reinterpret_cast<float4*>(dst + 4) = f1;
    }
}

extern "C" void kernel_launch(void* const* d_in, const int* in_sizes, int n_in,
                              void* d_out, int out_size, void* d_ws, size_t ws_size,
                              hipStream_t stream) {
    const int* mt = (const int*)d_in[0];
    float* ws = (float*)d_ws;
    P p;
    p.vpc  = (const float*)d_in[1];
    p.vpm  = (const float*)d_in[2];
    p.tpc  = (const float*)d_in[3];
    p.tpm  = (const float*)d_in[4];
    p.cpc  = (const float*)d_in[5];
    p.cpi  = (const float*)d_in[6];
    p.cpt  = (const float*)d_in[7];
    p.lig  = (const float*)d_in[8];
    p.lib  = (const float*)d_in[9];
    p.ltg  = (const float*)d_in[10];
    p.ltb  = (const float*)d_in[11];
    p.iw1  = (const float*)d_in[12];
    p.ib1  = (const float*)d_in[13];
    p.iw2  = (const float*)d_in[14];
    p.ib2  = (const float*)d_in[15];
    p.tw1  = (const float*)d_in[16];
    p.tb1  = (const float*)d_in[17];
    p.tw2  = (const float*)d_in[18];
    p.tb2  = (const float*)d_in[19];
    p.ciw1 = (const float*)d_in[20];
    p.cib1 = (const float*)d_in[21];
    p.ciw2 = (const float*)d_in[22];
    p.cib2 = (const float*)d_in[23];
    p.ctw1 = (const float*)d_in[24];
    p.ctb1 = (const float*)d_in[25];
    p.ctw2 = (const float*)d_in[26];
    p.ctb2 = (const float*)d_in[27];

    const bool packed = (ws_size >= F_END * sizeof(float));
    if (packed) {
        p.blob = (const u16*)(ws + F_BLOB);
        p.s1   = ws + F_S1;
        p.t1   = ws + F_T1;
        p.xi   = ws + F_XI;
        p.xt   = ws + F_XT;
        p.cimg = ws + F_CI;
        p.ctxt = ws + F_CT;
        constexpr u32 NPAIR = 12u * 1280 * 80 + 12u * 80 * 640;
        prep_pack_kernel<<<dim3((NPAIR + 255) / 256), dim3(256), 0, stream>>>(p, (u32*)(ws + F_BLOB));
        prep_fold_kernel<<<dim3(24), dim3(TPB), 0, stream>>>(p, ws + F_S1, ws + F_T1);
        chain8_kernel<<<dim3(72), dim3(TPB), 0, stream>>>(p);
    } else {
        p.blob = nullptr; p.s1 = nullptr; p.t1 = nullptr;
        p.xi   = ws + F_XI_U;
        p.xt   = ws + F_XT_U;
        p.cimg = ws + F_CI_U;
        p.ctxt = ws + F_CT_U;
        chain_fb_kernel<<<dim3(72), dim3(TPB), 0, stream>>>(p);
    }
    emit_kernel<<<dim3(4096), dim3(256), 0, stream>>>(mt, p.xi, p.xt, p.cimg, p.ctxt, (float*)d_out);
}